// Round 5
// baseline (1624.274 us; speedup 1.0000x reference)
//
#include <hip/hip_runtime.h>
#include <hip/hip_bf16.h>

// Qwen2 attention layer, MI355X/gfx950.
// B=2 S=2048 HID=3584 NH=28 NKV=4 D=128, causal, GQA groups=7.
// Round 5: attention occupancy push. KVBLK=32 -> 40 KB LDS -> 4 blocks/CU
// (16 waves/CU). Fused PV (V fragments read once, shared across both m).
// V^T tile rows are 64 B -> naturally bank-uniform, no swizzle needed.
// rope_qk vectorized x4.
//
// Workspace layout (bytes), total ~99.5 MB:
//   Xb    @ 0          29,360,128  (B*S x HID bf16)      -> reused as AOb after QKV GEMM
//   Wcat  @ 29,360,128 33,030,144  (4608 x 3584 bf16)    -> reused as Wo-bf16 after QKV GEMM
//   bcat  @ 62,390,272 18,432      (4608 f32)
//   QKVb  @ 62,408,704 37,748,736  (B*S x 4608 bf16)
//   Vt    @ 100,157,440 4,194,304  (B*NKV*128 x S bf16)

#define HID   3584
#define NHQ   28
#define NKVH  4
#define HD    128
#define SEQ   2048
#define NQKV  4608
#define GRP   7

typedef __attribute__((ext_vector_type(8))) short bf16x8;
typedef __attribute__((ext_vector_type(4))) float f32x4;

__device__ __forceinline__ void gload_lds16(const void* g, void* l) {
  __builtin_amdgcn_global_load_lds(
      (const __attribute__((address_space(1))) void*)g,
      (__attribute__((address_space(3))) void*)l, 16, 0, 0);
}

__device__ __forceinline__ unsigned short f2bf(float f) {
  __hip_bfloat16 h = __float2bfloat16(f);
  return *reinterpret_cast<unsigned short*>(&h);
}

__device__ __forceinline__ float bf2f(unsigned short u) {
  __hip_bfloat16 h = *reinterpret_cast<__hip_bfloat16*>(&u);
  return __bfloat162float(h);
}

// ---------------- f32 -> bf16 conversion (vectorized, 4 elems/thread) ------
__global__ __launch_bounds__(256)
void cvt_f32_bf16(const float* __restrict__ src, __hip_bfloat16* __restrict__ dst, int n4) {
  int i = blockIdx.x * 256 + threadIdx.x;
  if (i >= n4) return;
  float4 v = ((const float4*)src)[i];
  ushort4 o;
  o.x = f2bf(v.x); o.y = f2bf(v.y); o.z = f2bf(v.z); o.w = f2bf(v.w);
  ((ushort4*)dst)[i] = o;
}

__global__ __launch_bounds__(256)
void concat_bias(const float* __restrict__ bq, const float* __restrict__ bk,
                 const float* __restrict__ bv, float* __restrict__ out) {
  int i = blockIdx.x * 256 + threadIdx.x;
  if (i < HID) out[i] = bq[i];
  else if (i < HID + 512) out[i] = bk[i - HID];
  else if (i < NQKV) out[i] = bv[i - HID - 512];
}

// ---------------- GEMM: C[M][N] = A[M][K] * B[N][K]^T (+bias) --------------
// 128x128 tile, BK=32, 4 waves (2x2), mfma_f32_16x16x32_bf16 (m97 structure).
template<bool HAS_BIAS, bool OUT_BF16>
__global__ __launch_bounds__(256)
void gemm_bt(const __hip_bfloat16* __restrict__ A, const __hip_bfloat16* __restrict__ Bm,
             const float* __restrict__ bias, void* __restrict__ Cv,
             int M, int N, int K) {
  __shared__ __align__(16) __hip_bfloat16 As[128 * 32];
  __shared__ __align__(16) __hip_bfloat16 Bs[128 * 32];
  const int tid = threadIdx.x;
  const int w = tid >> 6, l = tid & 63;
  const int g = l >> 4, r = l & 15;
  const int wr = w >> 1, wc = w & 1;
  const int bm = blockIdx.x * 128;
  const int bn = blockIdx.y * 128;
  const int lr = l >> 2;        // 0..15: row within a 16-row staging chunk
  const int lc = (l & 3) * 8;   // 0/8/16/24: k-col offset within chunk

  f32x4 acc[4][4];
#pragma unroll
  for (int m = 0; m < 4; m++)
#pragma unroll
    for (int n = 0; n < 4; n++) acc[m][n] = (f32x4){0.f, 0.f, 0.f, 0.f};

  for (int k0 = 0; k0 < K; k0 += 32) {
#pragma unroll
    for (int i = 0; i < 2; i++) {
      const int rb = w * 32 + i * 16;
      gload_lds16(&A[(size_t)(bm + rb + lr) * K + k0 + lc], &As[rb * 32]);
      gload_lds16(&Bm[(size_t)(bn + rb + lr) * K + k0 + lc], &Bs[rb * 32]);
    }
    __syncthreads();
    bf16x8 af[4], bfr[4];
#pragma unroll
    for (int m = 0; m < 4; m++) af[m] = *(const bf16x8*)&As[(wr * 64 + m * 16 + r) * 32 + g * 8];
#pragma unroll
    for (int n = 0; n < 4; n++) bfr[n] = *(const bf16x8*)&Bs[(wc * 64 + n * 16 + r) * 32 + g * 8];
#pragma unroll
    for (int m = 0; m < 4; m++)
#pragma unroll
      for (int n = 0; n < 4; n++)
        acc[m][n] = __builtin_amdgcn_mfma_f32_16x16x32_bf16(af[m], bfr[n], acc[m][n], 0, 0, 0);
    __syncthreads();
  }

#pragma unroll
  for (int m = 0; m < 4; m++) {
#pragma unroll
    for (int n = 0; n < 4; n++) {
      const int gcol = bn + wc * 64 + n * 16 + r;
      const float bv = HAS_BIAS ? bias[gcol] : 0.f;
#pragma unroll
      for (int j = 0; j < 4; j++) {
        const int grow = bm + wr * 64 + m * 16 + 4 * g + j;
        float v = acc[m][n][j] + bv;
        if constexpr (OUT_BF16)
          ((__hip_bfloat16*)Cv)[(size_t)grow * N + gcol] = __float2bfloat16(v);
        else
          ((float*)Cv)[(size_t)grow * N + gcol] = v;
      }
    }
  }
}

// ---------------- RoPE on Q and K head slots (in-place, bf16, x4 vec) ------
__global__ __launch_bounds__(256)
void rope_qk(__hip_bfloat16* __restrict__ QKV, const float* __restrict__ cosb,
             const float* __restrict__ sinb) {
  int i = blockIdx.x * 256 + threadIdx.x;   // 2,097,152 threads
  int d = (i & 15) * 4;                      // 0..60, step 4
  int hh = (i >> 4) & 31;
  int row = i >> 9;                          // 0..4095 = b*S+s
  int cb = (hh < NHQ) ? hh * HD : HID + (hh - NHQ) * HD;
  unsigned short* base = (unsigned short*)QKV + (size_t)row * NQKV + cb;
  float4 c = *(const float4*)&cosb[row * HD + d];
  float4 sn = *(const float4*)&sinb[row * HD + d];
  ushort4 u1 = *(const ushort4*)(base + d);
  ushort4 u2 = *(const ushort4*)(base + d + 64);
  float x1[4] = {bf2f(u1.x), bf2f(u1.y), bf2f(u1.z), bf2f(u1.w)};
  float x2[4] = {bf2f(u2.x), bf2f(u2.y), bf2f(u2.z), bf2f(u2.w)};
  float cc[4] = {c.x, c.y, c.z, c.w};
  float ss[4] = {sn.x, sn.y, sn.z, sn.w};
  ushort4 o1, o2;
  o1.x = f2bf(x1[0] * cc[0] - x2[0] * ss[0]); o2.x = f2bf(x2[0] * cc[0] + x1[0] * ss[0]);
  o1.y = f2bf(x1[1] * cc[1] - x2[1] * ss[1]); o2.y = f2bf(x2[1] * cc[1] + x1[1] * ss[1]);
  o1.z = f2bf(x1[2] * cc[2] - x2[2] * ss[2]); o2.z = f2bf(x2[2] * cc[2] + x1[2] * ss[2]);
  o1.w = f2bf(x1[3] * cc[3] - x2[3] * ss[3]); o2.w = f2bf(x2[3] * cc[3] + x1[3] * ss[3]);
  *(ushort4*)(base + d) = o1;
  *(ushort4*)(base + d + 64) = o2;
}

// ---------------- V transpose: Vt[b][kv][d][s] = V[b][s][kv][d] ------------
__global__ __launch_bounds__(256)
void v_transpose(const __hip_bfloat16* __restrict__ QKV, __hip_bfloat16* __restrict__ Vt) {
  int i = blockIdx.x * 256 + threadIdx.x;   // 2*4*128*2048 = 2,097,152
  int s = i & (SEQ - 1);
  int d = (i >> 11) & (HD - 1);
  int kv = (i >> 18) & 3;
  int b = i >> 20;
  Vt[i] = QKV[(size_t)(b * SEQ + s) * NQKV + HID + 512 + kv * HD + d];
}

// ---------------- Flash attention: 4 waves x 32 q-rows, 32-col KV tiles ----
// Swapped QK^T: s = mfma(kf, qf) -> lane(g,r) holds S^T[kv=16ks+4g+j][q=r].
// Softmax per-lane + shfl_xor(16,32). P^T via per-wave swizzled LDS.
// Fused PV: each V fragment read once, shared by both m.
__global__ __launch_bounds__(256, 4)
void attn_fwd(const __hip_bfloat16* __restrict__ QKV, const __hip_bfloat16* __restrict__ Vt,
              __hip_bfloat16* __restrict__ AO) {
  const int qb = 15 - blockIdx.x;           // LPT: longest blocks first
  const int h = blockIdx.y;                 // 0..27
  const int b = blockIdx.z;                 // 0..1
  const int kvh = h / GRP;
  const int tid = threadIdx.x;
  const int w = tid >> 6, l = tid & 63;
  const int g = l >> 4, r = l & 15;
  const int qw = qb * 128 + w * 32;         // wave's first q row
  const float scl2 = 0.12751744055204955f;  // (1/sqrt(128)) * log2(e)
  const float NEGINF = -__builtin_inff();

  __shared__ __align__(16) __hip_bfloat16 Ks[2][32 * 128];   // 2x8 KB, swizzled
  __shared__ __align__(16) __hip_bfloat16 Vs[2][128 * 32];   // 2x8 KB, linear
  __shared__ __align__(16) __hip_bfloat16 Pl[4 * 2 * 16 * 32]; // 8 KB per-wave P^T

  const char* Kb = (const char*)(QKV + (size_t)(b * SEQ) * NQKV + HID + kvh * HD);
  const char* Vb = (const char*)(Vt + (size_t)((b * NKVH + kvh) * HD) * SEQ);
  const __hip_bfloat16* Qb = QKV + (size_t)(b * SEQ + qw) * NQKV + h * HD;

  // Q fragments (B-operand): qf[m][c] = Q[qw+16m+r][c*32 + g*8 ..]
  bf16x8 qf[2][4];
#pragma unroll
  for (int m = 0; m < 2; m++)
#pragma unroll
    for (int c = 0; c < 4; c++)
      qf[m][c] = *(const bf16x8*)&Qb[(size_t)(m * 16 + r) * NQKV + c * 32 + g * 8];

  f32x4 of[2][8];
#pragma unroll
  for (int m = 0; m < 2; m++)
#pragma unroll
    for (int db = 0; db < 8; db++) of[m][db] = (f32x4){0.f, 0.f, 0.f, 0.f};
  float mrow[2] = {-3e38f, -3e38f};
  float lsum[2] = {0.f, 0.f};

  const int ntiles = 4 * qb + 4;

  auto stage = [&](int buf, int kv0) {
#pragma unroll
    for (int p = 0; p < 2; p++) {
      const int row = w * 8 + p * 4 + (l >> 4);       // K tile row (0..31)
      const int cb = (l & 15) * 16;
      gload_lds16(Kb + (size_t)(kv0 + row) * (NQKV * 2) + (cb ^ ((row & 7) << 4)),
                  (char*)(Ks[buf]) + w * 2048 + p * 1024);
    }
#pragma unroll
    for (int p = 0; p < 2; p++) {
      const int row = w * 32 + p * 16 + (l >> 2);     // V^T tile row (= d, 0..127)
      const int cb = (l & 3) * 16;
      gload_lds16(Vb + (size_t)row * (SEQ * 2) + (size_t)kv0 * 2 + cb,
                  (char*)(Vs[buf]) + w * 2048 + p * 1024);
    }
  };

  stage(0, 0);
  __syncthreads();

  const int swz = (r & 7) << 4;      // K-tile swizzle (256 B rows)
  const int psw = (r & 3) << 4;      // P-tile swizzle (64 B rows)
  char* pw = (char*)Pl + w * 2048;

  for (int t = 0; t < ntiles; t++) {
    const int kv0 = t * 32;
    const int cur = t & 1;
    if (t + 1 < ntiles) stage(cur ^ 1, kv0 + 32);    // prefetch under compute

    if (kv0 <= qw + 31) {
      const bool do0 = (kv0 <= qw + 15);
      // ---- QK^T (swapped): s[m][ks], rows kv, cols q
      f32x4 s[2][2];
#pragma unroll
      for (int m = 0; m < 2; m++)
#pragma unroll
        for (int ks = 0; ks < 2; ks++) s[m][ks] = (f32x4){0.f, 0.f, 0.f, 0.f};
#pragma unroll
      for (int ks = 0; ks < 2; ks++) {
        const char* kp = (const char*)(Ks[cur]) + (ks * 16 + r) * 256;
        bf16x8 kf[4];
#pragma unroll
        for (int c = 0; c < 4; c++)
          kf[c] = *(const bf16x8*)(kp + ((c * 64 + g * 16) ^ swz));
        if (do0)
#pragma unroll
          for (int c = 0; c < 4; c++)
            s[0][ks] = __builtin_amdgcn_mfma_f32_16x16x32_bf16(kf[c], qf[0][c], s[0][ks], 0, 0, 0);
#pragma unroll
        for (int c = 0; c < 4; c++)
          s[1][ks] = __builtin_amdgcn_mfma_f32_16x16x32_bf16(kf[c], qf[1][c], s[1][ks], 0, 0, 0);
      }

      // ---- softmax (log2 domain) per m + P^T pack to LDS
#pragma unroll
      for (int m = 0; m < 2; m++) {
        if (m == 0 && !do0) continue;
        const int qm = qw + 16 * m + r;              // lane's q row
        float pm = -3e38f;
        if (kv0 + 31 <= qw + 16 * m) {               // interior: no mask
#pragma unroll
          for (int ks = 0; ks < 2; ks++)
#pragma unroll
            for (int j = 0; j < 4; j++) {
              s[m][ks][j] *= scl2;
              pm = fmaxf(pm, s[m][ks][j]);
            }
        } else {
#pragma unroll
          for (int ks = 0; ks < 2; ks++) {
            const int kvb = kv0 + 16 * ks + 4 * g;
#pragma unroll
            for (int j = 0; j < 4; j++) {
              s[m][ks][j] = (kvb + j <= qm) ? s[m][ks][j] * scl2 : NEGINF;
              pm = fmaxf(pm, s[m][ks][j]);
            }
          }
        }
        pm = fmaxf(pm, __shfl_xor(pm, 16));
        pm = fmaxf(pm, __shfl_xor(pm, 32));

        float rs = 0.f;
        if (__all(pm - mrow[m] <= 11.5f)) {          // defer-max: skip rescale
#pragma unroll
          for (int ks = 0; ks < 2; ks++)
#pragma unroll
            for (int j = 0; j < 4; j++) {
              float p = exp2f(s[m][ks][j] - mrow[m]);
              s[m][ks][j] = p;
              rs += p;
            }
        } else {
          const float nm = fmaxf(mrow[m], pm);
          const float al = exp2f(mrow[m] - nm);
          mrow[m] = nm;
#pragma unroll
          for (int ks = 0; ks < 2; ks++)
#pragma unroll
            for (int j = 0; j < 4; j++) {
              float p = exp2f(s[m][ks][j] - nm);
              s[m][ks][j] = p;
              rs += p;
            }
          lsum[m] *= al;
#pragma unroll
          for (int db = 0; db < 8; db++)
#pragma unroll
            for (int j = 0; j < 4; j++) of[m][db][j] *= al;
        }
        rs += __shfl_xor(rs, 16);
        rs += __shfl_xor(rs, 32);
        lsum[m] += rs;

        // ---- pack P^T pairs -> per-wave LDS [m][q=r][32 kv], swizzled b32
        char* pmw = pw + m * 1024 + r * 64;
#pragma unroll
        for (int ks = 0; ks < 2; ks++)
#pragma unroll
          for (int p = 0; p < 2; p++) {
            unsigned u = (unsigned)f2bf(s[m][ks][2 * p]) |
                         ((unsigned)f2bf(s[m][ks][2 * p + 1]) << 16);
            *(unsigned*)(pmw + ((ks * 32 + g * 8 + p * 4) ^ psw)) = u;
          }
      }

      // ---- PV fused: each V fragment read once, both m consume it
      bf16x8 pB0, pB1;
      if (do0) pB0 = *(const bf16x8*)(pw + r * 64 + ((g * 16) ^ psw));
      pB1 = *(const bf16x8*)(pw + 1024 + r * 64 + ((g * 16) ^ psw));
#pragma unroll
      for (int db = 0; db < 8; db++) {
        bf16x8 vf = *(const bf16x8*)((const char*)(Vs[cur]) + (db * 16 + r) * 64 + g * 16);
        if (do0) of[0][db] = __builtin_amdgcn_mfma_f32_16x16x32_bf16(vf, pB0, of[0][db], 0, 0, 0);
        of[1][db] = __builtin_amdgcn_mfma_f32_16x16x32_bf16(vf, pB1, of[1][db], 0, 0, 0);
      }
    }
    __syncthreads();   // drains prefetch + guards buffer reuse
  }

  // ---- epilogue: O^T in regs -> AO rows; lane stores 8B per (m,db)
  unsigned short* AOu = (unsigned short*)AO;
#pragma unroll
  for (int m = 0; m < 2; m++) {
    const float inv = 1.0f / lsum[m];
    const size_t rowb = (size_t)(b * SEQ + qw + 16 * m + r) * HID + h * HD;
#pragma unroll
    for (int db = 0; db < 8; db++) {
      ushort4 o;
      o.x = f2bf(of[m][db][0] * inv);
      o.y = f2bf(of[m][db][1] * inv);
      o.z = f2bf(of[m][db][2] * inv);
      o.w = f2bf(of[m][db][3] * inv);
      *(ushort4*)&AOu[rowb + db * 16 + 4 * g] = o;
    }
  }
}

// ---------------------------------------------------------------------------
extern "C" void kernel_launch(void* const* d_in, const int* in_sizes, int n_in,
                              void* d_out, int out_size, void* d_ws, size_t ws_size,
                              hipStream_t stream) {
  const float* hs = (const float*)d_in[0];
  const float* cosb = (const float*)d_in[1];
  const float* sinb = (const float*)d_in[2];
  const float* Wq = (const float*)d_in[3];
  const float* bq = (const float*)d_in[4];
  const float* Wk = (const float*)d_in[5];
  const float* bk = (const float*)d_in[6];
  const float* Wv = (const float*)d_in[7];
  const float* bv = (const float*)d_in[8];
  const float* Wo = (const float*)d_in[9];

  char* ws = (char*)d_ws;
  __hip_bfloat16* Xb = (__hip_bfloat16*)(ws);
  __hip_bfloat16* Wcat = (__hip_bfloat16*)(ws + 29360128);
  float* bcat = (float*)(ws + 62390272);
  __hip_bfloat16* QKVb = (__hip_bfloat16*)(ws + 62408704);
  __hip_bfloat16* Vt = (__hip_bfloat16*)(ws + 100157440);
  __hip_bfloat16* AOb = Xb;    // X dead after QKV GEMM
  __hip_bfloat16* Wob = Wcat;  // Wcat dead after QKV GEMM

  // Conversions to bf16
  cvt_f32_bf16<<<14336, 256, 0, stream>>>(hs, Xb, 3670016);                       // X
  cvt_f32_bf16<<<12544, 256, 0, stream>>>(Wq, Wcat, 3211264);                     // Wq rows 0..3583
  cvt_f32_bf16<<<1792, 256, 0, stream>>>(Wk, Wcat + (size_t)3584 * 3584, 458752); // Wk rows 3584..4095
  cvt_f32_bf16<<<1792, 256, 0, stream>>>(Wv, Wcat + (size_t)4096 * 3584, 458752); // Wv rows 4096..4607
  concat_bias<<<18, 256, 0, stream>>>(bq, bk, bv, bcat);

  // Fused QKV projection: [4096 x 3584] @ [4608 x 3584]^T + bias -> bf16
  dim3 gq(32, 36);
  gemm_bt<true, true><<<gq, 256, 0, stream>>>(Xb, Wcat, bcat, QKVb, 4096, NQKV, HID);

  // RoPE on Q + K head slots (in place, vectorized x4)
  rope_qk<<<8192, 256, 0, stream>>>(QKVb, cosb, sinb);

  // V transpose for PV fragment loads
  v_transpose<<<8192, 256, 0, stream>>>(QKVb, Vt);

  // Wo conversion (into the now-dead Wcat region)
  cvt_f32_bf16<<<12544, 256, 0, stream>>>(Wo, Wob, 3211264);

  // Flash attention: 128-row Q blocks, 4 waves x 32 rows, 32-col KV tiles
  dim3 ga(16, NHQ, 2);
  attn_fwd<<<ga, 256, 0, stream>>>(QKVb, Vt, AOb);

  // O projection -> f32 out
  dim3 go(32, 28);
  gemm_bt<false, false><<<go, 256, 0, stream>>>(AOb, Wob, nullptr, d_out, 4096, HID, HID);
}

// Round 6
// 599.144 us; speedup vs baseline: 2.7110x; 2.7110x over previous
//
#include <hip/hip_runtime.h>
#include <hip/hip_bf16.h>

// Qwen2 attention layer, MI355X/gfx950.
// B=2 S=2048 HID=3584 NH=28 NKV=4 D=128, causal, GQA groups=7.
// Round 6:
//  - GEMMs ported to 256x256 8-phase template (BK=64, 8 waves, dbuf LDS,
//    counted vmcnt(4), raw s_barrier, setprio around MFMA, XOR-swizzled LDS).
//  - Attention restored to round-4 structure (KVBLK=64, 2 blocks/CU) with
//    the proven fused-PV fix from round 5 (V fragments read once, shared by
//    both m). rope x4-vectorized.
//
// Workspace layout (bytes), total ~99.5 MB:
//   Xb    @ 0          29,360,128  (B*S x HID bf16)      -> reused as AOb after QKV GEMM
//   Wcat  @ 29,360,128 33,030,144  (4608 x 3584 bf16)    -> reused as Wo-bf16 after QKV GEMM
//   bcat  @ 62,390,272 18,432      (4608 f32)
//   QKVb  @ 62,408,704 37,748,736  (B*S x 4608 bf16)
//   Vt    @ 100,157,440 4,194,304  (B*NKV*128 x S bf16)

#define HID   3584
#define NHQ   28
#define NKVH  4
#define HD    128
#define SEQ   2048
#define NQKV  4608
#define GRP   7

typedef __attribute__((ext_vector_type(8))) short bf16x8;
typedef __attribute__((ext_vector_type(4))) float f32x4;

#define BARRIER() asm volatile("s_barrier" ::: "memory")

__device__ __forceinline__ void gload_lds16(const void* g, void* l) {
  __builtin_amdgcn_global_load_lds(
      (const __attribute__((address_space(1))) void*)g,
      (__attribute__((address_space(3))) void*)l, 16, 0, 0);
}

__device__ __forceinline__ unsigned short f2bf(float f) {
  __hip_bfloat16 h = __float2bfloat16(f);
  return *reinterpret_cast<unsigned short*>(&h);
}

__device__ __forceinline__ float bf2f(unsigned short u) {
  __hip_bfloat16 h = *reinterpret_cast<__hip_bfloat16*>(&u);
  return __bfloat162float(h);
}

// ---------------- f32 -> bf16 conversion (vectorized, 4 elems/thread) ------
__global__ __launch_bounds__(256)
void cvt_f32_bf16(const float* __restrict__ src, __hip_bfloat16* __restrict__ dst, int n4) {
  int i = blockIdx.x * 256 + threadIdx.x;
  if (i >= n4) return;
  float4 v = ((const float4*)src)[i];
  ushort4 o;
  o.x = f2bf(v.x); o.y = f2bf(v.y); o.z = f2bf(v.z); o.w = f2bf(v.w);
  ((ushort4*)dst)[i] = o;
}

__global__ __launch_bounds__(256)
void concat_bias(const float* __restrict__ bq, const float* __restrict__ bk,
                 const float* __restrict__ bv, float* __restrict__ out) {
  int i = blockIdx.x * 256 + threadIdx.x;
  if (i < HID) out[i] = bq[i];
  else if (i < HID + 512) out[i] = bk[i - HID];
  else if (i < NQKV) out[i] = bv[i - HID - 512];
}

// ---------------- GEMM: C[M][N] = A[M][K] * B[N][K]^T (+bias) --------------
// 256x256 tile, BK=64, 8 waves (2Mx4N), double-buffered LDS, 8-phase
// schedule with counted vmcnt (never drained to 0 in steady state).
// LDS: dbuf d at d*65536; A[256][64] at +0, B[256][64] at +32768.
// Swizzle: element (row, colByte) stored at colByte ^ ((row&7)<<4).
template<bool HAS_BIAS, bool OUT_BF16>
__global__ __launch_bounds__(512, 2)
void gemm256(const __hip_bfloat16* __restrict__ A, const __hip_bfloat16* __restrict__ Bm,
             const float* __restrict__ bias, void* __restrict__ Cv,
             int M, int N, int K) {
  __shared__ __align__(16) char lds[131072];
  const int tid = threadIdx.x;
  const int w = tid >> 6, l = tid & 63;
  const int g = l >> 4, r = l & 15;
  const int wr = w >> 2, wc = w & 3;
  const int bm = blockIdx.x * 256, bn = blockIdx.y * 256;
  const int NKT = K >> 6;
  const size_t Kb2 = (size_t)K * 2;
  const int swz = (r & 7) << 4;

  // stage half h (0:A-lo 1:A-hi 2:B-lo 3:B-hi) of K-tile kt into dbuf kt&1
  auto issueHalf = [&](int kt, int h) {
    const char* src = (h < 2) ? (const char*)A : (const char*)Bm;
    const int rbase = (h < 2) ? bm : bn;
    char* reg = lds + (kt & 1) * 65536 + ((h < 2) ? 0 : 32768);
#pragma unroll
    for (int i = 0; i < 2; ++i) {
      const int lrow = (h & 1) * 128 + w * 16 + i * 8;   // wave-uniform dest row
      const int row = lrow + (l >> 3);                    // per-lane source row
      const int cb = (l & 7) * 16;
      gload_lds16(src + (size_t)(rbase + row) * Kb2 + (size_t)kt * 128 + (cb ^ ((row & 7) << 4)),
                  reg + lrow * 128);
    }
  };

  auto ldA = [&](int d, int mf, int kk) -> bf16x8 {
    const int row = wr * 128 + mf * 16 + r;
    return *(const bf16x8*)(lds + d * 65536 + row * 128 + ((kk * 64 + g * 16) ^ swz));
  };
  auto ldB = [&](int d, int nf, int kk) -> bf16x8 {
    const int row = wc * 64 + nf * 16 + r;
    return *(const bf16x8*)(lds + d * 65536 + 32768 + row * 128 + ((kk * 64 + g * 16) ^ swz));
  };

  f32x4 acc[8][4];
#pragma unroll
  for (int m = 0; m < 8; m++)
#pragma unroll
    for (int n = 0; n < 4; n++) acc[m][n] = (f32x4){0.f, 0.f, 0.f, 0.f};

  // ---- prologue: stage kt0 + kt1 fully (16 loads/wave), wait for kt0
#pragma unroll
  for (int h = 0; h < 4; ++h) issueHalf(0, h);
#pragma unroll
  for (int h = 0; h < 4; ++h) issueHalf(1, h);
  asm volatile("s_waitcnt vmcnt(8)" ::: "memory");
  BARRIER();

  bf16x8 af[4][2], bfr[4][2];

#pragma unroll 1
  for (int kt = 0; kt < NKT; ++kt) {
    const int d = kt & 1;

    // ---- phase 0: A(r0) + B(c0) reads; stage kt+1's A-hi,B-hi; MFMA q0
    if (kt >= 1 && kt + 1 < NKT) { issueHalf(kt + 1, 1); issueHalf(kt + 1, 3); }
#pragma unroll
    for (int mf = 0; mf < 4; mf++)
#pragma unroll
      for (int kk = 0; kk < 2; kk++) af[mf][kk] = ldA(d, mf, kk);
#pragma unroll
    for (int nf = 0; nf < 2; nf++)
#pragma unroll
      for (int kk = 0; kk < 2; kk++) bfr[nf][kk] = ldB(d, nf, kk);
    BARRIER();
    __builtin_amdgcn_s_setprio(1);
#pragma unroll
    for (int mf = 0; mf < 4; mf++)
#pragma unroll
      for (int nf = 0; nf < 2; nf++)
#pragma unroll
        for (int kk = 0; kk < 2; kk++)
          acc[mf][nf] = __builtin_amdgcn_mfma_f32_16x16x32_bf16(af[mf][kk], bfr[nf][kk], acc[mf][nf], 0, 0, 0);
    __builtin_amdgcn_s_setprio(0);
    BARRIER();

    // ---- phase 1: B(c1) reads; MFMA q1 (A r0 reused)
#pragma unroll
    for (int nf = 2; nf < 4; nf++)
#pragma unroll
      for (int kk = 0; kk < 2; kk++) bfr[nf][kk] = ldB(d, nf, kk);
    BARRIER();
    __builtin_amdgcn_s_setprio(1);
#pragma unroll
    for (int mf = 0; mf < 4; mf++)
#pragma unroll
      for (int nf = 2; nf < 4; nf++)
#pragma unroll
        for (int kk = 0; kk < 2; kk++)
          acc[mf][nf] = __builtin_amdgcn_mfma_f32_16x16x32_bf16(af[mf][kk], bfr[nf][kk], acc[mf][nf], 0, 0, 0);
    __builtin_amdgcn_s_setprio(0);
    BARRIER();

    // ---- phase 2: A(r1) reads; stage kt+2's B-lo; MFMA q2 (B c0 reused)
    if (kt + 2 < NKT) issueHalf(kt + 2, 2);
#pragma unroll
    for (int mf = 0; mf < 4; mf++)
#pragma unroll
      for (int kk = 0; kk < 2; kk++) af[mf][kk] = ldA(d, mf + 4, kk);
    BARRIER();
    __builtin_amdgcn_s_setprio(1);
#pragma unroll
    for (int mf = 0; mf < 4; mf++)
#pragma unroll
      for (int nf = 0; nf < 2; nf++)
#pragma unroll
        for (int kk = 0; kk < 2; kk++)
          acc[mf + 4][nf] = __builtin_amdgcn_mfma_f32_16x16x32_bf16(af[mf][kk], bfr[nf][kk], acc[mf + 4][nf], 0, 0, 0);
    __builtin_amdgcn_s_setprio(0);
    BARRIER();

    // ---- phase 3: stage kt+2's A-lo; counted vmcnt; MFMA q3 (A r1, B c1)
    if (kt + 2 < NKT) {
      issueHalf(kt + 2, 0);
      asm volatile("s_waitcnt vmcnt(4)" ::: "memory");   // kt+1's 4 halves landed
    } else if (kt + 1 < NKT) {
      asm volatile("s_waitcnt vmcnt(0)" ::: "memory");   // epilogue drain
    }
    BARRIER();
    __builtin_amdgcn_s_setprio(1);
#pragma unroll
    for (int mf = 0; mf < 4; mf++)
#pragma unroll
      for (int nf = 2; nf < 4; nf++)
#pragma unroll
        for (int kk = 0; kk < 2; kk++)
          acc[mf + 4][nf] = __builtin_amdgcn_mfma_f32_16x16x32_bf16(af[mf][kk], bfr[nf][kk], acc[mf + 4][nf], 0, 0, 0);
    __builtin_amdgcn_s_setprio(0);
    BARRIER();
  }

  // ---- epilogue: acc -> C (+bias)
#pragma unroll
  for (int nf = 0; nf < 4; nf++) {
    const int gcol = bn + wc * 64 + nf * 16 + r;
    const float bv = HAS_BIAS ? bias[gcol] : 0.f;
#pragma unroll
    for (int mf = 0; mf < 8; mf++) {
#pragma unroll
      for (int j = 0; j < 4; j++) {
        const int grow = bm + wr * 128 + mf * 16 + 4 * g + j;
        float v = acc[mf][nf][j] + bv;
        if constexpr (OUT_BF16)
          ((__hip_bfloat16*)Cv)[(size_t)grow * N + gcol] = __float2bfloat16(v);
        else
          ((float*)Cv)[(size_t)grow * N + gcol] = v;
      }
    }
  }
}

// ---------------- RoPE on Q and K head slots (in-place, bf16, x4 vec) ------
__global__ __launch_bounds__(256)
void rope_qk(__hip_bfloat16* __restrict__ QKV, const float* __restrict__ cosb,
             const float* __restrict__ sinb) {
  int i = blockIdx.x * 256 + threadIdx.x;   // 2,097,152 threads
  int d = (i & 15) * 4;                      // 0..60, step 4
  int hh = (i >> 4) & 31;
  int row = i >> 9;                          // 0..4095 = b*S+s
  int cb = (hh < NHQ) ? hh * HD : HID + (hh - NHQ) * HD;
  unsigned short* base = (unsigned short*)QKV + (size_t)row * NQKV + cb;
  float4 c = *(const float4*)&cosb[row * HD + d];
  float4 sn = *(const float4*)&sinb[row * HD + d];
  ushort4 u1 = *(const ushort4*)(base + d);
  ushort4 u2 = *(const ushort4*)(base + d + 64);
  float x1[4] = {bf2f(u1.x), bf2f(u1.y), bf2f(u1.z), bf2f(u1.w)};
  float x2[4] = {bf2f(u2.x), bf2f(u2.y), bf2f(u2.z), bf2f(u2.w)};
  float cc[4] = {c.x, c.y, c.z, c.w};
  float ss[4] = {sn.x, sn.y, sn.z, sn.w};
  ushort4 o1, o2;
  o1.x = f2bf(x1[0] * cc[0] - x2[0] * ss[0]); o2.x = f2bf(x2[0] * cc[0] + x1[0] * ss[0]);
  o1.y = f2bf(x1[1] * cc[1] - x2[1] * ss[1]); o2.y = f2bf(x2[1] * cc[1] + x1[1] * ss[1]);
  o1.z = f2bf(x1[2] * cc[2] - x2[2] * ss[2]); o2.z = f2bf(x2[2] * cc[2] + x1[2] * ss[2]);
  o1.w = f2bf(x1[3] * cc[3] - x2[3] * ss[3]); o2.w = f2bf(x2[3] * cc[3] + x1[3] * ss[3]);
  *(ushort4*)(base + d) = o1;
  *(ushort4*)(base + d + 64) = o2;
}

// ---------------- V transpose: Vt[b][kv][d][s] = V[b][s][kv][d] ------------
__global__ __launch_bounds__(256)
void v_transpose(const __hip_bfloat16* __restrict__ QKV, __hip_bfloat16* __restrict__ Vt) {
  int i = blockIdx.x * 256 + threadIdx.x;   // 2*4*128*2048 = 2,097,152
  int s = i & (SEQ - 1);
  int d = (i >> 11) & (HD - 1);
  int kv = (i >> 18) & 3;
  int b = i >> 20;
  Vt[i] = QKV[(size_t)(b * SEQ + s) * NQKV + HID + 512 + kv * HD + d];
}

// ---------------- Flash attention: 4 waves x 32 q-rows, 64-col KV tiles ----
// Round-4 structure (proven 248 us) + fused PV from round 5 (proven correct):
// each V fragment read once from LDS, shared by both m.
__global__ __launch_bounds__(256, 2)
void attn_fwd(const __hip_bfloat16* __restrict__ QKV, const __hip_bfloat16* __restrict__ Vt,
              __hip_bfloat16* __restrict__ AO) {
  const int qb = 15 - blockIdx.x;           // LPT: longest blocks first
  const int h = blockIdx.y;                 // 0..27
  const int b = blockIdx.z;                 // 0..1
  const int kvh = h / GRP;
  const int tid = threadIdx.x;
  const int w = tid >> 6, l = tid & 63;
  const int g = l >> 4, r = l & 15;
  const int qw = qb * 128 + w * 32;         // wave's first q row
  const float scl2 = 0.12751744055204955f;  // (1/sqrt(128)) * log2(e)
  const float NEGINF = -__builtin_inff();

  __shared__ __align__(16) __hip_bfloat16 Ks[2][64 * 128];   // 2x16 KB, swizzled
  __shared__ __align__(16) __hip_bfloat16 Vs[2][128 * 64];   // 2x16 KB, swizzled
  __shared__ __align__(16) __hip_bfloat16 Pl[4 * 2 * 16 * 64]; // 16 KB per-wave P^T

  const char* Kb = (const char*)(QKV + (size_t)(b * SEQ) * NQKV + HID + kvh * HD);
  const char* Vb = (const char*)(Vt + (size_t)((b * NKVH + kvh) * HD) * SEQ);
  const __hip_bfloat16* Qb = QKV + (size_t)(b * SEQ + qw) * NQKV + h * HD;

  bf16x8 qf[2][4];
#pragma unroll
  for (int m = 0; m < 2; m++)
#pragma unroll
    for (int c = 0; c < 4; c++)
      qf[m][c] = *(const bf16x8*)&Qb[(size_t)(m * 16 + r) * NQKV + c * 32 + g * 8];

  f32x4 of[2][8];
#pragma unroll
  for (int m = 0; m < 2; m++)
#pragma unroll
    for (int db = 0; db < 8; db++) of[m][db] = (f32x4){0.f, 0.f, 0.f, 0.f};
  float mrow[2] = {-3e38f, -3e38f};
  float lsum[2] = {0.f, 0.f};

  const int ntiles = 2 * qb + 2;

  auto stage = [&](int buf, int kv0) {
#pragma unroll
    for (int p = 0; p < 4; p++) {
      const int row = w * 16 + p * 4 + (l >> 4);      // K tile row (local)
      const int cb = (l & 15) * 16;
      gload_lds16(Kb + (size_t)(kv0 + row) * (NQKV * 2) + (cb ^ ((row & 7) << 4)),
                  (char*)(Ks[buf]) + w * 4096 + p * 1024);
    }
#pragma unroll
    for (int p = 0; p < 4; p++) {
      const int row = w * 32 + p * 8 + (l >> 3);      // V^T tile row (= d)
      const int cb = (l & 7) * 16;
      gload_lds16(Vb + (size_t)row * (SEQ * 2) + (size_t)kv0 * 2 + (cb ^ ((row & 7) << 4)),
                  (char*)(Vs[buf]) + w * 4096 + p * 1024);
    }
  };

  stage(0, 0);
  __syncthreads();

  const int swz = (r & 7) << 4;
  char* pw = (char*)Pl + w * 4096;

  for (int t = 0; t < ntiles; t++) {
    const int kv0 = t * 64;
    const int cur = t & 1;
    if (t + 1 < ntiles) stage(cur ^ 1, kv0 + 64);    // prefetch under compute

    if (kv0 <= qw + 31) {
      const bool do0 = (kv0 <= qw + 15);
      // ---- QK^T (swapped): s[m][ks] = S^T tile, rows kv, cols q
      f32x4 s[2][4];
#pragma unroll
      for (int m = 0; m < 2; m++)
#pragma unroll
        for (int ks = 0; ks < 4; ks++) s[m][ks] = (f32x4){0.f, 0.f, 0.f, 0.f};
#pragma unroll
      for (int ks = 0; ks < 4; ks++) {
        const char* kp = (const char*)(Ks[cur]) + (ks * 16 + r) * 256;
        bf16x8 kf[4];
#pragma unroll
        for (int c = 0; c < 4; c++)
          kf[c] = *(const bf16x8*)(kp + ((c * 64 + g * 16) ^ swz));
        if (do0)
#pragma unroll
          for (int c = 0; c < 4; c++)
            s[0][ks] = __builtin_amdgcn_mfma_f32_16x16x32_bf16(kf[c], qf[0][c], s[0][ks], 0, 0, 0);
#pragma unroll
        for (int c = 0; c < 4; c++)
          s[1][ks] = __builtin_amdgcn_mfma_f32_16x16x32_bf16(kf[c], qf[1][c], s[1][ks], 0, 0, 0);
      }

      // ---- per-m softmax (log2 domain) + P^T pack to LDS
#pragma unroll
      for (int m = 0; m < 2; m++) {
        if (m == 0 && !do0) continue;
        const int qm = qw + 16 * m + r;              // lane's q row
        float pm = -3e38f;
        if (kv0 + 63 <= qw + 16 * m) {               // interior: no mask
#pragma unroll
          for (int ks = 0; ks < 4; ks++)
#pragma unroll
            for (int j = 0; j < 4; j++) {
              s[m][ks][j] *= scl2;
              pm = fmaxf(pm, s[m][ks][j]);
            }
        } else {
#pragma unroll
          for (int ks = 0; ks < 4; ks++) {
            const int kvb = kv0 + 16 * ks + 4 * g;
#pragma unroll
            for (int j = 0; j < 4; j++) {
              s[m][ks][j] = (kvb + j <= qm) ? s[m][ks][j] * scl2 : NEGINF;
              pm = fmaxf(pm, s[m][ks][j]);
            }
          }
        }
        pm = fmaxf(pm, __shfl_xor(pm, 16));
        pm = fmaxf(pm, __shfl_xor(pm, 32));

        float rs = 0.f;
        if (__all(pm - mrow[m] <= 11.5f)) {          // defer-max: skip rescale
#pragma unroll
          for (int ks = 0; ks < 4; ks++)
#pragma unroll
            for (int j = 0; j < 4; j++) {
              float p = exp2f(s[m][ks][j] - mrow[m]);
              s[m][ks][j] = p;
              rs += p;
            }
        } else {
          const float nm = fmaxf(mrow[m], pm);
          const float al = exp2f(mrow[m] - nm);
          mrow[m] = nm;
#pragma unroll
          for (int ks = 0; ks < 4; ks++)
#pragma unroll
            for (int j = 0; j < 4; j++) {
              float p = exp2f(s[m][ks][j] - nm);
              s[m][ks][j] = p;
              rs += p;
            }
          lsum[m] *= al;
#pragma unroll
          for (int db = 0; db < 8; db++)
#pragma unroll
            for (int j = 0; j < 4; j++) of[m][db][j] *= al;
        }
        rs += __shfl_xor(rs, 16);
        rs += __shfl_xor(rs, 32);
        lsum[m] += rs;

        // ---- pack P^T pairs -> per-wave LDS [m][q=r][64 kv], swizzled b32
        char* pmw = pw + m * 2048 + r * 128;
#pragma unroll
        for (int ks = 0; ks < 4; ks++)
#pragma unroll
          for (int p = 0; p < 2; p++) {
            unsigned u = (unsigned)f2bf(s[m][ks][2 * p]) |
                         ((unsigned)f2bf(s[m][ks][2 * p + 1]) << 16);
            *(unsigned*)(pmw + ((ks * 32 + g * 8 + p * 4) ^ swz)) = u;
          }
      }

      // ---- fused PV: each V fragment read once, shared by both m
      bf16x8 pB0[2], pB1[2];
#pragma unroll
      for (int kb = 0; kb < 2; kb++) {
        if (do0) pB0[kb] = *(const bf16x8*)(pw + r * 128 + ((kb * 64 + g * 16) ^ swz));
        pB1[kb] = *(const bf16x8*)(pw + 2048 + r * 128 + ((kb * 64 + g * 16) ^ swz));
      }
#pragma unroll
      for (int db = 0; db < 8; db++) {
        const char* vp = (const char*)(Vs[cur]) + (db * 16 + r) * 128;
#pragma unroll
        for (int kb = 0; kb < 2; kb++) {
          bf16x8 vf = *(const bf16x8*)(vp + ((kb * 64 + g * 16) ^ swz));
          if (do0) of[0][db] = __builtin_amdgcn_mfma_f32_16x16x32_bf16(vf, pB0[kb], of[0][db], 0, 0, 0);
          of[1][db] = __builtin_amdgcn_mfma_f32_16x16x32_bf16(vf, pB1[kb], of[1][db], 0, 0, 0);
        }
      }
    }
    __syncthreads();   // drains prefetch + guards buffer reuse
  }

  // ---- epilogue: O^T in regs -> AO rows; lane stores 8B per (m,db)
  unsigned short* AOu = (unsigned short*)AO;
#pragma unroll
  for (int m = 0; m < 2; m++) {
    const float inv = 1.0f / lsum[m];
    const size_t rowb = (size_t)(b * SEQ + qw + 16 * m + r) * HID + h * HD;
#pragma unroll
    for (int db = 0; db < 8; db++) {
      ushort4 o;
      o.x = f2bf(of[m][db][0] * inv);
      o.y = f2bf(of[m][db][1] * inv);
      o.z = f2bf(of[m][db][2] * inv);
      o.w = f2bf(of[m][db][3] * inv);
      *(ushort4*)&AOu[rowb + db * 16 + 4 * g] = o;
    }
  }
}

// ---------------------------------------------------------------------------
extern "C" void kernel_launch(void* const* d_in, const int* in_sizes, int n_in,
                              void* d_out, int out_size, void* d_ws, size_t ws_size,
                              hipStream_t stream) {
  const float* hs = (const float*)d_in[0];
  const float* cosb = (const float*)d_in[1];
  const float* sinb = (const float*)d_in[2];
  const float* Wq = (const float*)d_in[3];
  const float* bq = (const float*)d_in[4];
  const float* Wk = (const float*)d_in[5];
  const float* bk = (const float*)d_in[6];
  const float* Wv = (const float*)d_in[7];
  const float* bv = (const float*)d_in[8];
  const float* Wo = (const float*)d_in[9];

  char* ws = (char*)d_ws;
  __hip_bfloat16* Xb = (__hip_bfloat16*)(ws);
  __hip_bfloat16* Wcat = (__hip_bfloat16*)(ws + 29360128);
  float* bcat = (float*)(ws + 62390272);
  __hip_bfloat16* QKVb = (__hip_bfloat16*)(ws + 62408704);
  __hip_bfloat16* Vt = (__hip_bfloat16*)(ws + 100157440);
  __hip_bfloat16* AOb = Xb;    // X dead after QKV GEMM
  __hip_bfloat16* Wob = Wcat;  // Wcat dead after QKV GEMM

  // Conversions to bf16
  cvt_f32_bf16<<<14336, 256, 0, stream>>>(hs, Xb, 3670016);                       // X
  cvt_f32_bf16<<<12544, 256, 0, stream>>>(Wq, Wcat, 3211264);                     // Wq rows 0..3583
  cvt_f32_bf16<<<1792, 256, 0, stream>>>(Wk, Wcat + (size_t)3584 * 3584, 458752); // Wk rows 3584..4095
  cvt_f32_bf16<<<1792, 256, 0, stream>>>(Wv, Wcat + (size_t)4096 * 3584, 458752); // Wv rows 4096..4607
  concat_bias<<<18, 256, 0, stream>>>(bq, bk, bv, bcat);

  // Fused QKV projection: [4096 x 3584] @ [4608 x 3584]^T + bias -> bf16
  dim3 gq(16, 18);
  gemm256<true, true><<<gq, 512, 0, stream>>>(Xb, Wcat, bcat, QKVb, 4096, NQKV, HID);

  // RoPE on Q + K head slots (in place, vectorized x4)
  rope_qk<<<8192, 256, 0, stream>>>(QKVb, cosb, sinb);

  // V transpose for PV fragment loads
  v_transpose<<<8192, 256, 0, stream>>>(QKVb, Vt);

  // Wo conversion (into the now-dead Wcat region)
  cvt_f32_bf16<<<12544, 256, 0, stream>>>(Wo, Wob, 3211264);

  // Flash attention: 128-row Q blocks, 4 waves x 32 rows, 64-col KV tiles
  dim3 ga(16, NHQ, 2);
  attn_fwd<<<ga, 256, 0, stream>>>(QKVb, Vt, AOb);

  // O projection -> f32 out
  dim3 go(16, 14);
  gemm256<false, false><<<go, 512, 0, stream>>>(AOb, Wob, nullptr, d_out, 4096, HID, HID);
}